// Round 8
// baseline (510.884 us; speedup 1.0000x reference)
//
#include <hip/hip_runtime.h>
#include <hip/hip_bf16.h>
#include <stdint.h>

// VQ: x [N=131072, D=64] fp32, E [D=64, K=1024] fp32.
// R13: fp16 SINGLE-TERM screen. R5-R12 ablations: every schedule/staging
// variant lands 90-111 us; MfmaUtil*dur ~= the 25us MFMA floor of the 12-MFMA
// 3-term bf16 screen -> cut the work. fp16 1-term: err is a CLT sum of 64
// rounding terms, sigma~7.8e-4, gap-sigma~1.1e-3; TAU=0.02 (18sigma, 10sigma
// for max-norm rows) flags ~0.5% of rows into the proven exact fp64 refine.
// Per tile: 4 MFMA (was 12), 2 B loads (was 4), one 128KB fp16 B table.
// Geometry = best-measured family (256thr, grid 1024, pin+unroll2), B
// prefetch depth 2. Fused refine unchanged (math/tie-breaks identical).
// Verified facts used: A[m=lane&15][k=(lane>>4)*8+j] (m89/m91/m120, same for
// the 16x16x32 f16/bf16 family), C/D col=lane&15 row=(lane>>4)*4+reg
// (m89/m91, dtype-independent m121-m128), frag types 8xhalf / float4.

typedef unsigned long long u64;
typedef _Float16 half8 __attribute__((ext_vector_type(8)));
typedef float f32x4 __attribute__((ext_vector_type(4)));

constexpr int D = 64;
constexpr int K = 1024;
constexpr float TAU = 0.02f;     // 18-sigma screen-gap guard (see header)

// monotone fp32 -> u32 map (min preserved) — R3-proven
__device__ __forceinline__ uint32_t fmap(float v) {
    uint32_t u = __float_as_uint(v);
    return (u & 0x80000000u) ? ~u : (u | 0x80000000u);
}
__device__ __forceinline__ float funmap(uint32_t m) {
    uint32_t u = (m & 0x80000000u) ? (m ^ 0x80000000u) : ~m;
    return __uint_as_float(u);
}
__device__ __forceinline__ void top2_merge(u64& b, u64& s, u64 ob, u64 os) {
    if (ob < b) { s = (b < os) ? b : os; b = ob; }
    else        { s = (ob < s) ? ob : s; }
}
__device__ __forceinline__ u64 shfl_xor_u64(u64 v, int m) {
    uint32_t lo = (uint32_t)v, hi = (uint32_t)(v >> 32);
    lo = (uint32_t)__shfl_xor((int)lo, m, 64);
    hi = (uint32_t)__shfl_xor((int)hi, m, 64);
    return ((u64)hi << 32) | lo;
}
__device__ __forceinline__ double shfl_xor_f64(double v, int m) {
    int lo = __double2loint(v), hi = __double2hiint(v);
    lo = __shfl_xor(lo, m, 64);
    hi = __shfl_xor(hi, m, 64);
    return __hiloint2double(hi, lo);
}
// 8 fp32 -> 8 fp16 (RNE) fragment
__device__ __forceinline__ void cvt8h(float4 a, float4 b, half8& H) {
    H[0] = (_Float16)a.x; H[1] = (_Float16)a.y;
    H[2] = (_Float16)a.z; H[3] = (_Float16)a.w;
    H[4] = (_Float16)b.x; H[5] = (_Float16)b.y;
    H[6] = (_Float16)b.z; H[7] = (_Float16)b.w;
}

// ---- prep: e_sq (f64/f32), ET[k][d] gather table, Bh fragment-linear fp16
//      table of -2E. grid 256 x 256. ----
__global__ __launch_bounds__(256) void vq_prep(const float* __restrict__ E,
                                               double* __restrict__ e_sq64,
                                               float* __restrict__ e_sq32,
                                               float* __restrict__ ET,
                                               _Float16* __restrict__ Bh) {
    int tid = blockIdx.x * 256 + threadIdx.x;        // 0..65535
    if (tid < K) {
        int k = tid;
        double s = 0.0;
        for (int d = 0; d < D; ++d) {
            float v = E[d * K + k];
            s = fma((double)v, (double)v, s);
            ET[k * D + d] = v;
        }
        e_sq64[k] = s;
        e_sq32[k] = (float)s;
    }
    // table entry: frag f = t*2+c (t=tile 0..63, c=k-chunk 0..1), lane l, slot j
    //   value = fp16(-2*E[d][code]), d = 32c + 8*(l>>4) + j, code = 16t + (l&15)
    //   half8-frag index = t*128 + c*64 + l (tile t = 2KB contiguous)
    {
        int j = tid & 7;
        int l = (tid >> 3) & 63;
        int f = tid >> 9;            // 0..127
        int c = f & 1;
        int t = f >> 1;
        int d = 32 * c + 8 * (l >> 4) + j;
        int code = 16 * t + (l & 15);
        Bh[tid] = (_Float16)(-2.0f * E[d * K + code]);
    }
}

// ---- screen + fused exact refine: block = 128 rows (4 waves x 32) ----
__global__ __launch_bounds__(256, 4) void vq_screen(
    const float* __restrict__ x, const half8* __restrict__ Bh,
    const float* __restrict__ e_sq32, const double* __restrict__ e_sq64,
    const float* __restrict__ ET, float* __restrict__ out) {
    __shared__ float esq[K];                   // 4 KB
    __shared__ int bk[128];                    // 0.5 KB
    __shared__ double xs64[D];                 // 0.5 KB (refine staging)
    __shared__ double wbv[4];
    __shared__ int wbk_s[4];
    __shared__ int flag_list[128];             // 0.5 KB
    __shared__ int flag_n;

    const int t0 = threadIdx.x;
    const int base = blockIdx.x * 128;

    if (t0 == 0) flag_n = 0;

    // stage e_sq
    #pragma unroll
    for (int i = 0; i < 4; ++i) esq[i * 256 + t0] = e_sq32[i * 256 + t0];

    const int wid = t0 >> 6, l = t0 & 63;
    const int col = l & 15, quad = l >> 4;

    // A fragments for 2 rowsets, loaded DIRECTLY from global in fragment order
    // (verified layout: m = lane&15, k = quad*8 + j, k-chunks at 0 and 32),
    // converted to fp16 in registers.
    const int gr0 = base + wid * 32 + col;     // rowset a global row
    half8 Aa0, Aa1, Ab0, Ab1;
    {
        const float* xr = x + (size_t)gr0 * D + quad * 8;
        float4 p0 = *(const float4*)(xr);
        float4 p1 = *(const float4*)(xr + 4);
        float4 p2 = *(const float4*)(xr + 32);
        float4 p3 = *(const float4*)(xr + 36);
        const float* xs = xr + 16 * D;         // rowset b
        float4 q0 = *(const float4*)(xs);
        float4 q1 = *(const float4*)(xs + 4);
        float4 q2 = *(const float4*)(xs + 32);
        float4 q3 = *(const float4*)(xs + 36);
        cvt8h(p0, p1, Aa0);
        cvt8h(p2, p3, Aa1);
        cvt8h(q0, q1, Ab0);
        cvt8h(q2, q3, Ab1);
    }

    float besta[4], seca[4], bestb[4], secb[4];
    int bidxa[4], bidxb[4];
    #pragma unroll
    for (int r = 0; r < 4; ++r) {
        besta[r] = 3.4e38f; seca[r] = 3.4e38f; bidxa[r] = 0;
        bestb[r] = 3.4e38f; secb[r] = 3.4e38f; bidxb[r] = 0;
    }

    // B prefetch depth 2: hold tiles t (c), t+1 (n)
    half8 b0c = Bh[l],       b1c = Bh[64 + l];
    half8 b0n = Bh[128 + l], b1n = Bh[192 + l];

    __syncthreads();   // esq + flag_n ready

    float esv_c = esq[col];                    // tile 0
    float esv_n = esq[16 + col];               // tile 1

    #pragma unroll 2
    for (int t = 0; t < 64; ++t) {
        // prefetch tile t+2 (t>=62 wraps — valid memory, values unused)
        int tp = ((t + 2) & 63);
        half8 p0 = Bh[tp * 128 + l];
        half8 p1 = Bh[tp * 128 + 64 + l];
        float esv_p = esq[tp * 16 + col];
        // pin: loads above may not sink below, MFMAs below may not hoist above
        // (R8: without this the compiler sinks the loads -> per-tile L2 stall).
        __builtin_amdgcn_sched_barrier(0);

        f32x4 Ca = {esv_c, esv_c, esv_c, esv_c};
        f32x4 Cb = {esv_c, esv_c, esv_c, esv_c};
        // two independent 2-chains (rowsets a/b) -> ILP for the matrix pipe
        Ca = __builtin_amdgcn_mfma_f32_16x16x32_f16(Aa0, b0c, Ca, 0, 0, 0);
        Cb = __builtin_amdgcn_mfma_f32_16x16x32_f16(Ab0, b0c, Cb, 0, 0, 0);
        Ca = __builtin_amdgcn_mfma_f32_16x16x32_f16(Aa1, b1c, Ca, 0, 0, 0);
        Cb = __builtin_amdgcn_mfma_f32_16x16x32_f16(Ab1, b1c, Cb, 0, 0, 0);

        int tc = t * 16;
        #pragma unroll
        for (int r = 0; r < 4; ++r) {
            float va = Ca[r];
            bool lta = va < besta[r];
            float mxa = fmaxf(va, besta[r]);
            besta[r] = fminf(va, besta[r]);
            seca[r]  = fminf(seca[r], mxa);
            bidxa[r] = lta ? tc : bidxa[r];
            float vb = Cb[r];
            bool ltb = vb < bestb[r];
            float mxb = fmaxf(vb, bestb[r]);
            bestb[r] = fminf(vb, bestb[r]);
            secb[r]  = fminf(secb[r], mxb);
            bidxb[r] = ltb ? tc : bidxb[r];
        }
        b0c = b0n; b1c = b1n; b0n = p0; b1n = p1;
        esv_c = esv_n; esv_n = esv_p;
    }

    // per-register reduce across the 16 col-lanes (masks 1..8 preserve quad)
    #pragma unroll
    for (int r = 0; r < 4; ++r) {
        {   // rowset a
            u64 b = ((u64)fmap(besta[r]) << 32) | (uint32_t)(bidxa[r] + col);
            u64 s = ((u64)fmap(seca[r]) << 32) | 0xFFFFFFFFu;
            #pragma unroll
            for (int m = 8; m >= 1; m >>= 1) {
                u64 ob = shfl_xor_u64(b, m);
                u64 os = shfl_xor_u64(s, m);
                top2_merge(b, s, ob, os);
            }
            if (col == 0) {
                int rowL = wid * 32 + quad * 4 + r;       // verified C row map
                bk[rowL] = (int)(uint32_t)(b & 0xFFFFFFFFu);
                float vb = funmap((uint32_t)(b >> 32));
                float vs = funmap((uint32_t)(s >> 32));
                if (vs - vb < TAU) {
                    int idx = atomicAdd(&flag_n, 1);
                    flag_list[idx] = rowL;
                }
            }
        }
        {   // rowset b
            u64 b = ((u64)fmap(bestb[r]) << 32) | (uint32_t)(bidxb[r] + col);
            u64 s = ((u64)fmap(secb[r]) << 32) | 0xFFFFFFFFu;
            #pragma unroll
            for (int m = 8; m >= 1; m >>= 1) {
                u64 ob = shfl_xor_u64(b, m);
                u64 os = shfl_xor_u64(s, m);
                top2_merge(b, s, ob, os);
            }
            if (col == 0) {
                int rowL = wid * 32 + 16 + quad * 4 + r;
                bk[rowL] = (int)(uint32_t)(b & 0xFFFFFFFFu);
                float vb = funmap((uint32_t)(b >> 32));
                float vs = funmap((uint32_t)(s >> 32));
                if (vs - vb < TAU) {
                    int idx = atomicAdd(&flag_n, 1);
                    flag_list[idx] = rowL;
                }
            }
        }
    }
    __syncthreads();

    // fused exact refine for flagged rows (~0.6 rows/block expected at TAU=.02).
    // Identical math + tie-breaks to the proven vq_refine kernel:
    // ET[k*D+d] == E[d*K+k] exactly; fp64 fma over ascending d; v<best with
    // ascending k; wave reduce then cross-wave lowest-k-on-tie merge.
    {
        int nf = flag_n;                         // uniform across block
        for (int f = 0; f < nf; ++f) {
            int rowR = flag_list[f];
            if (t0 < D) xs64[t0] = (double)x[(size_t)(base + rowR) * D + t0];
            __syncthreads();
            double best = 1.0e300; int bestk = 0;
            #pragma unroll
            for (int j = 0; j < 4; ++j) {
                int k = t0 * 4 + j;
                const float* ep = ET + (size_t)k * D;
                double a = 0.0;
                #pragma unroll 4
                for (int d = 0; d < D; ++d)
                    a = fma(xs64[d], (double)ep[d], a);
                double v = fma(-2.0, a, e_sq64[k]);
                if (v < best) { best = v; bestk = k; }
            }
            #pragma unroll
            for (int m = 32; m >= 1; m >>= 1) {
                double ov = shfl_xor_f64(best, m);
                int    ok = __shfl_xor(bestk, m, 64);
                if (ov < best || (ov == best && ok < bestk)) { best = ov; bestk = ok; }
            }
            if ((t0 & 63) == 0) { wbv[t0 >> 6] = best; wbk_s[t0 >> 6] = bestk; }
            __syncthreads();
            if (t0 == 0) {
                double bv = wbv[0]; int bb = wbk_s[0];
                for (int w = 1; w < 4; ++w)
                    if (wbv[w] < bv || (wbv[w] == bv && wbk_s[w] < bb)) { bv = wbv[w]; bb = wbk_s[w]; }
                bk[rowR] = bb;
            }
            __syncthreads();
        }
    }

    // gather: thread t0 copies 128 B of its row from ET
    {
        int row = t0 >> 1, seg = t0 & 1;
        const float4* ep = (const float4*)(ET + (size_t)bk[row] * D + seg * 32);
        float4* op = (float4*)(out + (size_t)(base + row) * D + seg * 32);
        #pragma unroll
        for (int q = 0; q < 8; ++q) op[q] = ep[q];
    }
}

extern "C" void kernel_launch(void* const* d_in, const int* in_sizes, int n_in,
                              void* d_out, int out_size, void* d_ws, size_t ws_size,
                              hipStream_t stream) {
    const float* x = (const float*)d_in[0];
    const float* E = (const float*)d_in[1];
    float* out = (float*)d_out;
    int N = in_sizes[0] / D;   // 131072

    // ws: e_sq64 8K | e_sq32 4K | ET 256K | Bh 128K (fp16)
    char* w = (char*)d_ws;
    double*    e_sq64 = (double*)w;     w += K * sizeof(double);
    float*     e_sq32 = (float*)w;      w += K * sizeof(float);
    float*     ET     = (float*)w;      w += (size_t)K * D * sizeof(float);
    _Float16*  Bh     = (_Float16*)w;   w += (size_t)K * D * sizeof(_Float16);

    vq_prep<<<256, 256, 0, stream>>>(E, e_sq64, e_sq32, ET, Bh);
    vq_screen<<<N / 128, 256, 0, stream>>>(x, (const half8*)Bh,
                                           e_sq32, e_sq64, ET, out);
}

// Round 9
// 288.598 us; speedup vs baseline: 1.7702x; 1.7702x over previous
//
#include <hip/hip_runtime.h>
#include <hip/hip_bf16.h>
#include <stdint.h>

// VQ: x [N=131072, D=64] fp32, E [D=64, K=1024] fp32.
// R14: fp16 1-term screen kept; refine ARCHITECTURE fixed + deeper
// amortization. R13 post-mortem: screen MFMA work was fine (MfmaUtil*dur =
// 8us) but TAU=0.02 flagged thousands of rows into a block-serial fp64 refine
// (4 barriers + 64-deep chains + 256KB ET sweep per row) -> 456us. Fixes:
// (1) TAU=0.01 (11-sigma; R13 validated 0.02 end-to-end, absmax=0).
// (2) per-WAVE-parallel refine: flagged rows striped across waves (f+=4),
//     lane l owns 16 codes, x in wave-private LDS strip, zero barriers in the
//     refine, 64-lane butterfly with the proven tie-break (lowest k on ties).
// (3) 4 rowsets/wave (64 rows/wave, 256/block, grid 512): R6's amortization
//     mechanism again — per tile 8 MFMA as 4 independent depth-2 chains and
//     only 2 B loads; launch_bounds(256,2) -> 256-VGPR cap, no spill risk.
// Verified facts used: A[m=lane&15][k=(lane>>4)*8+j] (m89/m91/m120, f16/bf16
// family), C/D col=lane&15 row=(lane>>4)*4+reg (m89/m91, dtype-independent
// m121-m128), frag types 8xhalf / float4.

typedef unsigned long long u64;
typedef _Float16 half8 __attribute__((ext_vector_type(8)));
typedef float f32x4 __attribute__((ext_vector_type(4)));

constexpr int D = 64;
constexpr int K = 1024;
constexpr float TAU = 0.01f;     // ~11-sigma screen-gap guard (R13 ran 0.02 clean)

// monotone fp32 -> u32 map (min preserved) — R3-proven
__device__ __forceinline__ uint32_t fmap(float v) {
    uint32_t u = __float_as_uint(v);
    return (u & 0x80000000u) ? ~u : (u | 0x80000000u);
}
__device__ __forceinline__ float funmap(uint32_t m) {
    uint32_t u = (m & 0x80000000u) ? (m ^ 0x80000000u) : ~m;
    return __uint_as_float(u);
}
__device__ __forceinline__ void top2_merge(u64& b, u64& s, u64 ob, u64 os) {
    if (ob < b) { s = (b < os) ? b : os; b = ob; }
    else        { s = (ob < s) ? ob : s; }
}
__device__ __forceinline__ u64 shfl_xor_u64(u64 v, int m) {
    uint32_t lo = (uint32_t)v, hi = (uint32_t)(v >> 32);
    lo = (uint32_t)__shfl_xor((int)lo, m, 64);
    hi = (uint32_t)__shfl_xor((int)hi, m, 64);
    return ((u64)hi << 32) | lo;
}
__device__ __forceinline__ double shfl_xor_f64(double v, int m) {
    int lo = __double2loint(v), hi = __double2hiint(v);
    lo = __shfl_xor(lo, m, 64);
    hi = __shfl_xor(hi, m, 64);
    return __hiloint2double(hi, lo);
}
// 8 fp32 -> 8 fp16 (RNE) fragment
__device__ __forceinline__ void cvt8h(float4 a, float4 b, half8& H) {
    H[0] = (_Float16)a.x; H[1] = (_Float16)a.y;
    H[2] = (_Float16)a.z; H[3] = (_Float16)a.w;
    H[4] = (_Float16)b.x; H[5] = (_Float16)b.y;
    H[6] = (_Float16)b.z; H[7] = (_Float16)b.w;
}

// ---- prep: e_sq (f64/f32), ET[k][d] gather table, Bh fragment-linear fp16
//      table of -2E. grid 256 x 256. ----
__global__ __launch_bounds__(256) void vq_prep(const float* __restrict__ E,
                                               double* __restrict__ e_sq64,
                                               float* __restrict__ e_sq32,
                                               float* __restrict__ ET,
                                               _Float16* __restrict__ Bh) {
    int tid = blockIdx.x * 256 + threadIdx.x;        // 0..65535
    if (tid < K) {
        int k = tid;
        double s = 0.0;
        for (int d = 0; d < D; ++d) {
            float v = E[d * K + k];
            s = fma((double)v, (double)v, s);
            ET[k * D + d] = v;
        }
        e_sq64[k] = s;
        e_sq32[k] = (float)s;
    }
    // table entry: frag f = t*2+c (t=tile 0..63, c=k-chunk 0..1), lane l, slot j
    //   value = fp16(-2*E[d][code]), d = 32c + 8*(l>>4) + j, code = 16t + (l&15)
    //   half8-frag index = t*128 + c*64 + l (tile t = 2KB contiguous)
    {
        int j = tid & 7;
        int l = (tid >> 3) & 63;
        int f = tid >> 9;            // 0..127
        int c = f & 1;
        int t = f >> 1;
        int d = 32 * c + 8 * (l >> 4) + j;
        int code = 16 * t + (l & 15);
        Bh[tid] = (_Float16)(-2.0f * E[d * K + code]);
    }
}

// ---- screen + per-wave refine: block = 256 rows (4 waves x 64) ----
__global__ __launch_bounds__(256, 2) void vq_screen(
    const float* __restrict__ x, const half8* __restrict__ Bh,
    const float* __restrict__ e_sq32, const double* __restrict__ e_sq64,
    const float* __restrict__ ET, float* __restrict__ out) {
    __shared__ float esq[K];                   // 4 KB
    __shared__ int bk[256];                    // 1 KB
    __shared__ double xsw[4][D];               // 2 KB (per-wave refine staging)
    __shared__ int flag_list[256];             // 1 KB
    __shared__ int flag_n;

    const int t0 = threadIdx.x;
    const int base = blockIdx.x * 256;

    if (t0 == 0) flag_n = 0;

    // stage e_sq
    #pragma unroll
    for (int i = 0; i < 4; ++i) esq[i * 256 + t0] = e_sq32[i * 256 + t0];

    const int wid = t0 >> 6, l = t0 & 63;
    const int col = l & 15, quad = l >> 4;

    // A fragments for 4 rowsets (wave owns rows [wid*64, wid*64+64)),
    // loaded DIRECTLY from global in fragment order (verified layout:
    // m = lane&15, k = quad*8 + j, k-chunks at 0 and 32), fp16 in registers.
    half8 A0[4], A1[4];
    #pragma unroll
    for (int s = 0; s < 4; ++s) {
        const float* xr = x + (size_t)(base + wid * 64 + s * 16 + col) * D + quad * 8;
        float4 p0 = *(const float4*)(xr);
        float4 p1 = *(const float4*)(xr + 4);
        float4 p2 = *(const float4*)(xr + 32);
        float4 p3 = *(const float4*)(xr + 36);
        cvt8h(p0, p1, A0[s]);
        cvt8h(p2, p3, A1[s]);
    }

    float best[4][4], sec[4][4];
    int bidx[4][4];
    #pragma unroll
    for (int s = 0; s < 4; ++s)
        #pragma unroll
        for (int r = 0; r < 4; ++r) {
            best[s][r] = 3.4e38f; sec[s][r] = 3.4e38f; bidx[s][r] = 0;
        }

    // B prefetch depth 2: tiles t (c), t+1 (n)
    half8 b0c = Bh[l],       b1c = Bh[64 + l];
    half8 b0n = Bh[128 + l], b1n = Bh[192 + l];

    __syncthreads();   // esq + flag_n ready

    float esv_c = esq[col];                    // tile 0
    float esv_n = esq[16 + col];               // tile 1

    #pragma unroll 2
    for (int t = 0; t < 64; ++t) {
        // prefetch tile t+2 (t>=62 wraps — valid memory, values unused)
        int tp = ((t + 2) & 63);
        half8 p0 = Bh[tp * 128 + l];
        half8 p1 = Bh[tp * 128 + 64 + l];
        float esv_p = esq[tp * 16 + col];
        // pin: loads above may not sink below, MFMAs below may not hoist above
        // (R8: without this the compiler sinks the loads -> per-tile L2 stall).
        __builtin_amdgcn_sched_barrier(0);

        int tc = t * 16;
        // 4 independent depth-2 MFMA chains (one per rowset) -> matrix-pipe ILP
        #pragma unroll
        for (int s = 0; s < 4; ++s) {
            f32x4 C = {esv_c, esv_c, esv_c, esv_c};
            C = __builtin_amdgcn_mfma_f32_16x16x32_f16(A0[s], b0c, C, 0, 0, 0);
            C = __builtin_amdgcn_mfma_f32_16x16x32_f16(A1[s], b1c, C, 0, 0, 0);
            #pragma unroll
            for (int r = 0; r < 4; ++r) {
                float v = C[r];
                bool lt = v < best[s][r];
                float mx = fmaxf(v, best[s][r]);
                best[s][r] = fminf(v, best[s][r]);
                sec[s][r]  = fminf(sec[s][r], mx);
                bidx[s][r] = lt ? tc : bidx[s][r];
            }
        }
        b0c = b0n; b1c = b1n; b0n = p0; b1n = p1;
        esv_c = esv_n; esv_n = esv_p;
    }

    // per-register reduce across the 16 col-lanes (masks 1..8 preserve quad)
    #pragma unroll
    for (int s = 0; s < 4; ++s)
        #pragma unroll
        for (int r = 0; r < 4; ++r) {
            u64 b = ((u64)fmap(best[s][r]) << 32) | (uint32_t)(bidx[s][r] + col);
            u64 sv = ((u64)fmap(sec[s][r]) << 32) | 0xFFFFFFFFu;
            #pragma unroll
            for (int m = 8; m >= 1; m >>= 1) {
                u64 ob = shfl_xor_u64(b, m);
                u64 os = shfl_xor_u64(sv, m);
                top2_merge(b, sv, ob, os);
            }
            if (col == 0) {
                int rowL = wid * 64 + s * 16 + quad * 4 + r;  // verified C row map
                bk[rowL] = (int)(uint32_t)(b & 0xFFFFFFFFu);
                float vb = funmap((uint32_t)(b >> 32));
                float vs = funmap((uint32_t)(sv >> 32));
                if (vs - vb < TAU) {
                    int idx = atomicAdd(&flag_n, 1);
                    flag_list[idx] = rowL;
                }
            }
        }
    __syncthreads();

    // per-WAVE-parallel exact fp64 refine: flagged rows striped across waves,
    // each wave refines a row alone (no barriers). Lane l owns codes
    // k = l*16..l*16+15 (ascending within lane, strict < keeps lowest k);
    // 64-lane butterfly keeps lowest k on exact ties -> identical semantics
    // to the R2/R3-proven refine (ET[k*D+d] == E[d*K+k] exactly, fp64 fma
    // ascending d, e_sq64 C-term).
    {
        int nf = flag_n;                         // uniform across block
        for (int f = wid; f < nf; f += 4) {
            int rowR = flag_list[f];
            xsw[wid][l] = (double)x[(size_t)(base + rowR) * D + l];
            asm volatile("s_waitcnt lgkmcnt(0)" ::: "memory");
            __builtin_amdgcn_sched_barrier(0);   // rule #18: fence the ds reads
            double bestd = 1.0e300; int bestk = 0;
            #pragma unroll 4
            for (int j = 0; j < 16; ++j) {
                int k = l * 16 + j;
                const float* ep = ET + (size_t)k * D;
                double a = 0.0;
                #pragma unroll 8
                for (int d = 0; d < D; ++d)
                    a = fma(xsw[wid][d], (double)ep[d], a);
                double v = fma(-2.0, a, e_sq64[k]);
                if (v < bestd) { bestd = v; bestk = k; }
            }
            #pragma unroll
            for (int m = 32; m >= 1; m >>= 1) {
                double ov = shfl_xor_f64(bestd, m);
                int    ok = __shfl_xor(bestk, m, 64);
                if (ov < bestd || (ov == bestd && ok < bestk)) { bestd = ov; bestk = ok; }
            }
            if (l == 0) bk[rowR] = bestk;
        }
    }
    __syncthreads();

    // gather: thread t0 copies its whole row (256 B) from ET
    {
        const float4* ep = (const float4*)(ET + (size_t)bk[t0] * D);
        float4* op = (float4*)(out + (size_t)(base + t0) * D);
        #pragma unroll
        for (int q = 0; q < 16; ++q) op[q] = ep[q];
    }
}

extern "C" void kernel_launch(void* const* d_in, const int* in_sizes, int n_in,
                              void* d_out, int out_size, void* d_ws, size_t ws_size,
                              hipStream_t stream) {
    const float* x = (const float*)d_in[0];
    const float* E = (const float*)d_in[1];
    float* out = (float*)d_out;
    int N = in_sizes[0] / D;   // 131072

    // ws: e_sq64 8K | e_sq32 4K | ET 256K | Bh 128K (fp16)
    char* w = (char*)d_ws;
    double*    e_sq64 = (double*)w;     w += K * sizeof(double);
    float*     e_sq32 = (float*)w;      w += K * sizeof(float);
    float*     ET     = (float*)w;      w += (size_t)K * D * sizeof(float);
    _Float16*  Bh     = (_Float16*)w;   w += (size_t)K * D * sizeof(_Float16);

    vq_prep<<<256, 256, 0, stream>>>(E, e_sq64, e_sq32, ET, Bh);
    vq_screen<<<N / 256, 256, 0, stream>>>(x, (const half8*)Bh,
                                           e_sq32, e_sq64, ET, out);
}